// Round 4
// baseline (148.661 us; speedup 1.0000x reference)
//
#include <hip/hip_runtime.h>
#include <stdint.h>

#define WW 1024
#define HH 1024
#define NB 4
#define HW (HH * WW)
#define NPIX (NB * HW)        // 4194304
#define NT 4096               // 32x32 tiles per input
#define INVALID 0xFFFFFFFFu
#define RS 8                  // rows per open strip

// counter layout (uint32 words), ALL zero-init by one 16640-B memset:
//   bank b misc at b*16: [0]=~min_bits (atomicMax of complement; values>=0 so
//                         bit order == float order and init-0 is identity)
//                        [1]=max_bits [2]=root0 flag
//   [32] = done counter (k_border last-block final reduce)
//   fg/comp u64 slots: FCW(b,s) = 64   + (b*64+s)*16   (64 slots/bank, 64B stride)
//   link u32 slots:    LKW(b,s) = 2112 + (b*64+s)*16
#define FCW(b,s) (64 + ((b)*64+(s))*16)
#define LKW(b,s) (2112 + ((b)*64+(s))*16)
#define CNT_BYTES 16640

// ---- open strip: cross erode+dilate + per-input min/max (core verified) ----
__device__ __forceinline__ void do_open_strip(const float* __restrict__ in,
                                              float* __restrict__ out,
                                              uint32_t* c, int strip, uint32_t* S) {
    int b  = strip >> 7;
    int y0 = (strip & 127) * RS;
    int t  = threadIdx.x;
    float* sx = (float*)S;
    float* sw = (float*)S + 2580;
    float* smin = (float*)S + 5160;
    float* smax = (float*)S + 5164;
    const float4* inb = (const float4*)(in + (size_t)b * HW);
    float4* outb      = (float4*)(out + (size_t)b * HW);

    float4 A[RS + 4];
    #pragma unroll
    for (int j = 0; j < RS + 4; j++) {
        int iy = y0 - 2 + j;
        if (iy >= 0 && iy < HH) A[j] = inb[iy * 256 + t];
        else A[j] = make_float4(1e10f, 1e10f, 1e10f, 1e10f);  // erosion pad
    }
    #pragma unroll
    for (int rr = 0; rr < RS + 2; rr++) { sx[rr * 258 + t + 1] = A[rr + 1].x; sw[rr * 258 + t + 1] = A[rr + 1].w; }
    if (t < RS + 2) { sw[t * 258 + 0] = 1e10f; sx[t * 258 + 257] = 1e10f; }
    __syncthreads();

    float4 E[RS + 2];
    #pragma unroll
    for (int rr = 0; rr < RS + 2; rr++) {
        int ey = y0 - 1 + rr;
        float lw = sw[rr * 258 + t], rw = sx[rr * 258 + t + 2];
        float4 v = A[rr + 1];
        float hx = fminf(fminf(lw, v.x), v.y);
        float hy = fminf(fminf(v.x, v.y), v.z);
        float hz = fminf(fminf(v.y, v.z), v.w);
        float hw = fminf(fminf(v.z, v.w), rw);
        float4 e;
        e.x = fminf(hx, fminf(A[rr].x, A[rr + 2].x));
        e.y = fminf(hy, fminf(A[rr].y, A[rr + 2].y));
        e.z = fminf(hz, fminf(A[rr].z, A[rr + 2].z));
        e.w = fminf(hw, fminf(A[rr].w, A[rr + 2].w));
        if (ey < 0 || ey >= HH) e = make_float4(-1e10f, -1e10f, -1e10f, -1e10f);
        E[rr] = e;
    }
    __syncthreads();

    #pragma unroll
    for (int d = 0; d < RS; d++) { sx[d * 258 + t + 1] = E[d + 1].x; sw[d * 258 + t + 1] = E[d + 1].w; }
    if (t < RS) { sw[t * 258 + 0] = -1e10f; sx[t * 258 + 257] = -1e10f; }
    __syncthreads();

    float lmin = __uint_as_float(0x7F800000u);
    float lmax = 0.0f;
    #pragma unroll
    for (int d = 0; d < RS; d++) {
        float lw = sw[d * 258 + t], rw = sx[d * 258 + t + 2];
        float4 v = E[d + 1];
        float hx = fmaxf(fmaxf(lw, v.x), v.y);
        float hy = fmaxf(fmaxf(v.x, v.y), v.z);
        float hz = fmaxf(fmaxf(v.y, v.z), v.w);
        float hw = fmaxf(fmaxf(v.z, v.w), rw);
        float4 o;
        o.x = fmaxf(hx, fmaxf(E[d].x, E[d + 2].x));
        o.y = fmaxf(hy, fmaxf(E[d].y, E[d + 2].y));
        o.z = fmaxf(hz, fmaxf(E[d].z, E[d + 2].z));
        o.w = fmaxf(hw, fmaxf(E[d].w, E[d + 2].w));
        outb[(y0 + d) * 256 + t] = o;
        lmin = fminf(lmin, fminf(fminf(o.x, o.y), fminf(o.z, o.w)));
        lmax = fmaxf(lmax, fmaxf(fmaxf(o.x, o.y), fmaxf(o.z, o.w)));
    }
    for (int off = 32; off > 0; off >>= 1) {
        lmin = fminf(lmin, __shfl_down(lmin, off));
        lmax = fmaxf(lmax, __shfl_down(lmax, off));
    }
    if ((t & 63) == 0) { smin[t >> 6] = lmin; smax[t >> 6] = lmax; }
    __syncthreads();
    if (t == 0) {
        float m0 = fminf(fminf(smin[0], smin[1]), fminf(smin[2], smin[3]));
        float m1 = fmaxf(fmaxf(smax[0], smax[1]), fmaxf(smax[2], smax[3]));
        atomicMax(&c[0], ~__float_as_uint(m0));  // complement: min via max, init 0 ok
        atomicMax(&c[1], __float_as_uint(m1));
    }
}

// exact binarize threshold: smallest float B with (B-mn)/denom >= 0.5;
// v >= B is then bitwise identical to the reference predicate for every v.
__device__ __forceinline__ float calc_thr(const uint32_t* c, int bank) {
    float mn = __uint_as_float(~c[bank * 16 + 0]);
    float mx = __uint_as_float(c[bank * 16 + 1]);
    float denom = (mx - mn) + 1e-10f;   // reference association order
    uint32_t lo = 0, hi = 0x7F800000u;
    while (lo < hi) {
        uint32_t mid = (lo + hi) >> 1;
        float q = (__uint_as_float(mid) - mn) / denom;  // IEEE f32 div
        if (q >= 0.5f) hi = mid; else lo = mid + 1;
    }
    return __uint_as_float(lo);
}

// ---------------- LDS union-find (wave-private region) ----------------------
__device__ __forceinline__ uint32_t lload(uint32_t* lp, uint32_t x) {
    return __hip_atomic_load(&lp[x], __ATOMIC_RELAXED, __HIP_MEMORY_SCOPE_WORKGROUP);
}
__device__ __forceinline__ uint32_t lfind(uint32_t* lp, uint32_t x) {
    uint32_t p = lload(lp, x);
    while (p != x) {
        uint32_t gp = lload(lp, p);
        if (gp != p)
            __hip_atomic_store(&lp[x], gp, __ATOMIC_RELAXED, __HIP_MEMORY_SCOPE_WORKGROUP);
        x = p; p = gp;
    }
    return x;
}
__device__ uint32_t lunion(uint32_t* lp, uint32_t a, uint32_t b) {
    uint32_t ra = lfind(lp, a), rb = lfind(lp, b);
    while (ra != rb) {
        uint32_t hi = ra > rb ? ra : rb;
        uint32_t lo = ra ^ rb ^ hi;
        uint32_t old = atomicCAS(&lp[lo], lo, hi);
        if (old == lo) return 1;  // killed exactly one root
        ra = lfind(lp, old);
        rb = lfind(lp, hi);
    }
    return 0;
}
__device__ __forceinline__ int run_len(uint32_t bits) {  // consecutive 1s from bit 0
    return (int)__builtin_ctzll(~(uint64_t)bits);
}

// ---- binarize + tile-local run CCL + compact border-node emit --------------
// tail: per-wave packed stat -> LDS slot; caller combines 4 waves -> 1 atomic.
__device__ void do_ccl_tile(const float* __restrict__ opened, uint8_t* __restrict__ desc,
                            uint32_t* __restrict__ parent, uint32_t* cbase, int bank,
                            int tile, int L, uint32_t* M, uint32_t* LP, uint32_t* SM,
                            float thr, uint32_t* pkslot) {
    int b  = tile >> 10;
    int tt = tile & 1023;
    int ty0 = (tt >> 5) << 5;
    int tx0 = (tt & 31) << 5;
    uint32_t base = (uint32_t)b * HW + (uint32_t)ty0 * WW + tx0;

    #pragma unroll
    for (int q = 0; q < 4; q++) {
        uint32_t u = (uint32_t)L + 64u * q;
        ((uint4*)LP)[u] = make_uint4(4*u, 4*u+1, 4*u+2, 4*u+3);
        ((uint4*)SM)[u] = make_uint4(INVALID, INVALID, INVALID, INVALID);
    }

    // dense loads: lane L covers row (L>>3)+8q, cols (L&7)*4..+3
    int r8 = L >> 3, c8 = (L & 7) << 2;
    uint32_t fgcnt = 0;
    #pragma unroll
    for (int q = 0; q < 4; q++) {
        int rr = r8 + 8 * q;
        float4 v = *(const float4*)(opened + base + (uint32_t)rr * WW + c8);
        uint32_t pb = (v.x >= thr ? 1u : 0u) | (v.y >= thr ? 2u : 0u)
                    | (v.z >= thr ? 4u : 0u) | (v.w >= thr ? 8u : 0u);
        fgcnt += __popc(pb);
        uint32_t part = pb << c8;
        part |= __shfl_xor(part, 1, 8);
        part |= __shfl_xor(part, 2, 8);
        part |= __shfl_xor(part, 4, 8);
        if ((L & 7) == 0) M[rr] = part;
    }
    __syncthreads();

    // unions: lane owns half-row (r = L>>1, half h = L&1)
    int r = L >> 1, h = L & 1;
    uint32_t rowm = M[r];
    uint32_t halfsel = 0xFFFFu << (16 * h);
    uint32_t starts = (rowm & ~(rowm << 1)) & halfsel;
    uint32_t runs = __popc(starts);
    uint32_t links = 0;
    if (r > 0 && starts) {
        uint32_t up = M[r - 1];
        uint32_t w0 = starts;
        while (w0) {
            int lx = __builtin_ctz(w0); w0 &= w0 - 1;
            int e = lx + run_len(rowm >> lx) - 1;
            int lo = lx ? lx - 1 : 0;
            int hi = (e >= 31) ? 31 : e + 1;
            uint32_t hm = (hi == 31) ? 0xFFFFFFFFu : ((1u << (hi + 1)) - 1u);
            uint32_t w = up & hm & ~((1u << lo) - 1u);
            uint32_t repA = ((uint32_t)r << 5) + e;
            while (w) {
                int xs = __builtin_ctz(w);
                int xe = xs + run_len(up >> xs) - 1;
                links += lunion(LP, repA, (((uint32_t)r - 1) << 5) + (uint32_t)xe);
                w = (xe >= 31) ? 0u : (w & ~((1u << (xe + 1)) - 1u));
            }
        }
    }
    __syncthreads();

    // pixel-0 / label-0: isolated fg singleton at pixel 0 (all nbrs intra-tile)
    if (tile == 0 && L == 0) {
        if ((rowm & 1u) && !(rowm & 2u) && LP[0] == 0u) atomicOr(&cbase[bank * 16 + 2], 1u);
    }

    // border slot assignment: lane handles positions 2L, 2L+1; lfind from the
    // pixel's RUN REP (run end) — non-rep pixels are never linked in LP.
    uint32_t rk[2]; bool fgk[2];
    #pragma unroll
    for (int j = 0; j < 2; j++) {
        int k = 2 * L + j;
        int li = (k < 32) ? k
               : (k < 64) ? (31 * 32 + (k - 32))
               : (k < 96) ? ((k - 64) << 5)
                          : (((k - 96) << 5) + 31);
        int ly = li >> 5, lx = li & 31;
        uint32_t rm = M[ly];
        bool f = (rm >> lx) & 1u;
        fgk[j] = f;
        if (f) {
            int e = lx + run_len(rm >> lx) - 1;
            rk[j] = lfind(LP, ((uint32_t)ly << 5) + (uint32_t)e);
            atomicMin(&SM[rk[j]], (uint32_t)k);
        }
    }
    __syncthreads();

    uint32_t nodebase = (uint32_t)tile << 7;
    uint32_t d2 = 0;
    #pragma unroll
    for (int j = 0; j < 2; j++) {
        int k = 2 * L + j;
        uint32_t sb = 0xFFu;
        if (fgk[j]) {
            uint32_t s = SM[rk[j]];
            sb = s;
            if (s == (uint32_t)k) parent[nodebase + k] = nodebase + k;  // canonical only
        }
        d2 |= sb << (8 * j);
    }
    ((uint16_t*)desc)[((uint32_t)tile << 6) + L] = (uint16_t)d2;

    uint32_t pk = (fgcnt << 20) | (runs << 10) | links;
    for (int off = 32; off > 0; off >>= 1) pk += __shfl_down(pk, off);
    if (L == 0) *pkslot = pk;     // per-wave LDS slot; block combines -> 1 atomic
    __syncthreads();
}

// ---------------- global union-find on compact nodes (device scope) ---------
__device__ __forceinline__ uint32_t pload(uint32_t* P, uint32_t x) {
    return __hip_atomic_load(&P[x], __ATOMIC_RELAXED, __HIP_MEMORY_SCOPE_AGENT);
}
__device__ __forceinline__ uint32_t uf_find(uint32_t* P, uint32_t x) {
    uint32_t p = pload(P, x);
    while (p != x) {
        uint32_t gp = pload(P, p);
        if (gp != p)
            __hip_atomic_store(&P[x], gp, __ATOMIC_RELAXED, __HIP_MEMORY_SCOPE_AGENT);
        x = p; p = gp;
    }
    return x;
}
__device__ uint32_t uf_union(uint32_t* P, uint32_t a, uint32_t b) {
    uint32_t ra = uf_find(P, a);
    uint32_t rb = uf_find(P, b);
    while (ra != rb) {
        uint32_t hi = ra > rb ? ra : rb;
        uint32_t lo = ra ^ rb ^ hi;
        uint32_t old = atomicCAS(&P[lo], lo, hi);
        if (old == lo) return 1;  // killed exactly one root
        ra = uf_find(P, old);
        rb = uf_find(P, hi);
    }
    return 0;
}

// ---------------- kernels: both inputs per dispatch -------------------------
__global__ void k_open2(const float* __restrict__ img, const float* __restrict__ lab,
                        float* __restrict__ op0, float* __restrict__ op1,
                        uint32_t* cbase) {
    __shared__ uint32_t S[5168];
    int bank = blockIdx.x >> 9;
    do_open_strip(bank ? lab : img, bank ? op1 : op0, cbase + bank * 16,
                  blockIdx.x & 511, S);
}

__global__ __launch_bounds__(256) void k_ccl2(const float* __restrict__ op0,
                                              const float* __restrict__ op1,
                                              uint8_t* __restrict__ d0,
                                              uint8_t* __restrict__ d1,
                                              uint32_t* __restrict__ p0,
                                              uint32_t* __restrict__ p1,
                                              uint32_t* cbase) {
    __shared__ uint32_t S[8324];
    int bank = blockIdx.x >> 10;
    int wave = threadIdx.x >> 6, L = threadIdx.x & 63;
    uint32_t* M = S + wave * 2080;
    float thr = calc_thr(cbase, bank);
    int tile = ((blockIdx.x & 1023) << 2) + wave;
    do_ccl_tile(bank ? op1 : op0, bank ? d1 : d0, bank ? p1 : p0, cbase, bank,
                tile, L, M, M + 32, M + 1056, thr, &S[8320 + wave]);
    if (threadIdx.x == 0) {
        uint32_t fg = 0, comp = 0;
        #pragma unroll
        for (int w = 0; w < 4; w++) {
            uint32_t pk = S[8320 + w];
            fg   += pk >> 20;
            comp += ((pk >> 10) & 1023u) - (pk & 1023u);   // per-tile runs-links >= 0
        }
        if (fg | comp)
            atomicAdd((unsigned long long*)&cbase[FCW(bank, blockIdx.x & 63)],
                      ((unsigned long long)comp << 32) | fg);
    }
}

// cross-tile edges: candidate (a,b) pairs (r3-identical dedup set) are pushed
// into a per-block LDS queue, then unioned by ALL 256 threads round-robin —
// critical path ~1 union/thread instead of up to 3 serial per lane. UF kill
// count is order-invariant (each node's self->nonself transition happens
// exactly once), so `links` is exactly preserved.
__global__ __launch_bounds__(256) void k_border(const uint8_t* __restrict__ desc0,
                                                const uint8_t* __restrict__ desc1,
                                                uint32_t* __restrict__ parent0,
                                                uint32_t* __restrict__ parent1,
                                                uint32_t* cbase,
                                                float* __restrict__ out) {
    __shared__ unsigned long long Q[800];   // worst case 4*190+8 = 768 pairs
    __shared__ uint32_t qn;
    __shared__ uint32_t SW[6];
    __shared__ unsigned long long SB[4];
    int inb  = blockIdx.x >> 10;
    int wave = threadIdx.x >> 6, L = threadIdx.x & 63;
    int tile = ((blockIdx.x & 1023) << 2) + wave;
    const uint8_t* desc = inb ? desc1 : desc0;
    uint32_t* parent = inb ? parent1 : parent0;

    if (threadIdx.x == 0) qn = 0;
    __syncthreads();

    // ---- pair generation (per wave, per tile) ----
    {
        int tt = tile & 1023;
        int tyy = tt >> 5, txx = tt & 31;
        const uint8_t* dT = desc + ((uint32_t)tile << 7);
        uint32_t nT = (uint32_t)tile << 7;

        bool east  = (L < 32);
        int  x     = L & 31;
        bool valid = east ? (txx < 31) : (tyy < 31);
        int  tP    = east ? (tile + 1) : (tile + 32);
        uint32_t nP = (uint32_t)tP << 7;
        uint32_t sA = (uint32_t)dT[(east ? 96 : 32) + x];          // own-edge slot
        const uint8_t* dP = desc + (((uint32_t)tP << 7) + (east ? 64u : 0u));
        uint32_t t = valid ? (uint32_t)dP[x] : 0xFFu;              // partner slot

        uint32_t tp1  = __shfl(t,  L + 1);
        uint32_t tm1  = __shfl(t,  L - 1);
        uint32_t sAp1 = __shfl(sA, L + 1);
        uint32_t sAm1 = __shfl(sA, L - 1);

        if (valid && sA != 0xFFu) {
            uint32_t a = nT + sA;
            if (t != 0xFFu && !(x > 0 && sAm1 == sA && tm1 == t)) {
                uint32_t i = atomicAdd(&qn, 1u);
                Q[i] = ((unsigned long long)a << 32) | (nP + t);
            }
            if (x < 31 && tp1 != 0xFFu && tp1 != t && sAp1 != sA) {
                uint32_t i = atomicAdd(&qn, 1u);
                Q[i] = ((unsigned long long)a << 32) | (nP + tp1);
            }
            if (x > 0 && tm1 != 0xFFu && tm1 != t && sAm1 != sA) {
                uint32_t i = atomicAdd(&qn, 1u);
                Q[i] = ((unsigned long long)a << 32) | (nP + tm1);
            }
        }
        if (L == 0 && tyy < 31 && txx < 31) {        // SE corner
            int tSE = tile + 33;
            uint32_t sB = dT[63];
            uint32_t sQ = desc[((uint32_t)tSE << 7)];
            if (sB != 0xFFu && sQ != 0xFFu) {
                uint32_t i = atomicAdd(&qn, 1u);
                Q[i] = ((unsigned long long)(nT + sB) << 32) | (((uint32_t)tSE << 7) + sQ);
            }
        }
        if (L == 1 && tyy < 31 && txx > 0) {         // SW corner
            int tSW = tile + 31;
            uint32_t sB = dT[32];
            uint32_t sQ = desc[((uint32_t)tSW << 7) + 31];
            if (sB != 0xFFu && sQ != 0xFFu) {
                uint32_t i = atomicAdd(&qn, 1u);
                Q[i] = ((unsigned long long)(nT + sB) << 32) | (((uint32_t)tSW << 7) + sQ);
            }
        }
    }
    __syncthreads();

    // ---- rebalanced union phase: all 256 threads share the queue ----
    uint32_t n = qn;
    uint32_t links = 0;
    for (uint32_t i = threadIdx.x; i < n; i += 256) {
        unsigned long long q = Q[i];
        links += uf_union(parent, (uint32_t)(q >> 32), (uint32_t)q);
    }

    for (int off = 32; off > 0; off >>= 1) links += __shfl_down(links, off);
    if (L == 0) SW[wave] = links;
    __syncthreads();
    if (threadIdx.x == 0) {
        uint32_t lk = SW[0] + SW[1] + SW[2] + SW[3];
        if (lk) atomicAdd(&cbase[LKW(inb, blockIdx.x & 63)], lk);
        // order our slot-add before the ticket WITHOUT an agent-release
        // (acq_rel RMW emits L2 cache maintenance per block — the r2
        // regression). All cross-block data moves through device-scope
        // atomics (coherent point), so a plain vmem drain suffices.
        asm volatile("s_waitcnt vmcnt(0)" ::: "memory");
        uint32_t old = __hip_atomic_fetch_add(&cbase[32], 1u,
                                              __ATOMIC_RELAXED, __HIP_MEMORY_SCOPE_AGENT);
        SW[4] = old;
    }
    __syncthreads();
    if (SW[4] == 2047u) {   // last of 2048 blocks: fused final reduce
        unsigned long long acc;
        if (wave == 0)
            acc = __hip_atomic_load((unsigned long long*)&cbase[FCW(0, L)],
                                    __ATOMIC_RELAXED, __HIP_MEMORY_SCOPE_AGENT);
        else if (wave == 1)
            acc = __hip_atomic_load((unsigned long long*)&cbase[FCW(1, L)],
                                    __ATOMIC_RELAXED, __HIP_MEMORY_SCOPE_AGENT);
        else if (wave == 2)
            acc = __hip_atomic_load(&cbase[LKW(0, L)],
                                    __ATOMIC_RELAXED, __HIP_MEMORY_SCOPE_AGENT);
        else
            acc = __hip_atomic_load(&cbase[LKW(1, L)],
                                    __ATOMIC_RELAXED, __HIP_MEMORY_SCOPE_AGENT);
        for (int off = 32; off > 0; off >>= 1) acc += __shfl_down(acc, off);
        if (L == 0) SB[wave] = acc;
        __syncthreads();
        if (threadIdx.x == 0) {
            unsigned long long a0 = SB[0], a1 = SB[1];
            uint32_t gl0 = (uint32_t)SB[2], gl1 = (uint32_t)SB[3];
            uint32_t nf0 = (uint32_t)a0, lc0 = (uint32_t)(a0 >> 32);
            uint32_t nf1 = (uint32_t)a1, lc1 = (uint32_t)(a1 >> 32);
            uint32_t z0 = __hip_atomic_load(&cbase[2],  __ATOMIC_RELAXED, __HIP_MEMORY_SCOPE_AGENT);
            uint32_t z1 = __hip_atomic_load(&cbase[18], __ATOMIC_RELAXED, __HIP_MEMORY_SCOPE_AGENT);
            uint32_t comps0 = lc0 - gl0;   // total fg components (incl. pixel-0 singleton)
            uint32_t comps1 = lc1 - gl1;
            float ccs  = (float)(comps0 - z0 + ((nf0 < (uint32_t)NPIX || z0) ? 1u : 0u));
            float ccsg = (float)(comps1 - z1 + ((nf1 < (uint32_t)NPIX || z1) ? 1u : 0u));
            out[0] = fabsf(ccsg - ccs) / (float)nf1;   // all exact ints < 2^24
        }
    }
}

extern "C" void kernel_launch(void* const* d_in, const int* in_sizes, int n_in,
                              void* d_out, int out_size, void* d_ws, size_t ws_size,
                              hipStream_t stream) {
    const float* img = (const float*)d_in[0];
    const float* lab = (const float*)d_in[1];
    float* out = (float*)d_out;
    char* ws = (char*)d_ws;

    float*    op0 = (float*)ws;                                      // 16 MB
    float*    op1 = (float*)(ws + (size_t)16 * 1024 * 1024);         // 16 MB
    uint8_t*  d0  = (uint8_t*)(ws + (size_t)32 * 1024 * 1024);       // 512 KB
    uint8_t*  d1  = (uint8_t*)(ws + (size_t)32 * 1024 * 1024 + 512 * 1024);
    uint32_t* p0  = (uint32_t*)(ws + (size_t)33 * 1024 * 1024);      // 2 MB
    uint32_t* p1  = (uint32_t*)(ws + (size_t)35 * 1024 * 1024);      // 2 MB
    uint32_t* cnt = (uint32_t*)(ws + (size_t)37 * 1024 * 1024);      // 16640 B

    hipMemsetAsync(cnt, 0, CNT_BYTES, stream);
    k_open2<<<2 * NB * (HH / RS), 256, 0, stream>>>(img, lab, op0, op1, cnt);
    k_ccl2<<<2 * NT / 4, 256, 0, stream>>>(op0, op1, d0, d1, p0, p1, cnt);
    k_border<<<2 * NT / 4, 256, 0, stream>>>(d0, d1, p0, p1, cnt, out);
}

// Round 5
// 143.734 us; speedup vs baseline: 1.0343x; 1.0343x over previous
//
#include <hip/hip_runtime.h>
#include <stdint.h>

#define WW 1024
#define HH 1024
#define NB 4
#define HW (HH * WW)
#define NPIX (NB * HW)        // 4194304
#define NT 4096               // 32x32 tiles per input
#define INVALID 0xFFFFFFFFu
#define RS 8                  // rows per open strip

// counter layout (uint32 words), ALL zero-init by one 16640-B memset:
//   bank b misc at b*16: [0]=~min_bits (atomicMax of complement; values>=0 so
//                         bit order == float order and init-0 is identity)
//                        [1]=max_bits [2]=root0 flag
//   [32] = done counter (k_border last-block final reduce)
//   fg/comp u64 slots: FCW(b,s) = 64   + (b*64+s)*16   (64 slots/bank, 64B stride)
//   link u32 slots:    LKW(b,s) = 2112 + (b*64+s)*16
#define FCW(b,s) (64 + ((b)*64+(s))*16)
#define LKW(b,s) (2112 + ((b)*64+(s))*16)
#define CNT_BYTES 16640

// ---- open strip: cross erode+dilate + per-input min/max (core verified) ----
__device__ __forceinline__ void do_open_strip(const float* __restrict__ in,
                                              float* __restrict__ out,
                                              uint32_t* c, int strip, uint32_t* S) {
    int b  = strip >> 7;
    int y0 = (strip & 127) * RS;
    int t  = threadIdx.x;
    float* sx = (float*)S;
    float* sw = (float*)S + 2580;
    float* smin = (float*)S + 5160;
    float* smax = (float*)S + 5164;
    const float4* inb = (const float4*)(in + (size_t)b * HW);
    float4* outb      = (float4*)(out + (size_t)b * HW);

    float4 A[RS + 4];
    #pragma unroll
    for (int j = 0; j < RS + 4; j++) {
        int iy = y0 - 2 + j;
        if (iy >= 0 && iy < HH) A[j] = inb[iy * 256 + t];
        else A[j] = make_float4(1e10f, 1e10f, 1e10f, 1e10f);  // erosion pad
    }
    #pragma unroll
    for (int rr = 0; rr < RS + 2; rr++) { sx[rr * 258 + t + 1] = A[rr + 1].x; sw[rr * 258 + t + 1] = A[rr + 1].w; }
    if (t < RS + 2) { sw[t * 258 + 0] = 1e10f; sx[t * 258 + 257] = 1e10f; }
    __syncthreads();

    float4 E[RS + 2];
    #pragma unroll
    for (int rr = 0; rr < RS + 2; rr++) {
        int ey = y0 - 1 + rr;
        float lw = sw[rr * 258 + t], rw = sx[rr * 258 + t + 2];
        float4 v = A[rr + 1];
        float hx = fminf(fminf(lw, v.x), v.y);
        float hy = fminf(fminf(v.x, v.y), v.z);
        float hz = fminf(fminf(v.y, v.z), v.w);
        float hw = fminf(fminf(v.z, v.w), rw);
        float4 e;
        e.x = fminf(hx, fminf(A[rr].x, A[rr + 2].x));
        e.y = fminf(hy, fminf(A[rr].y, A[rr + 2].y));
        e.z = fminf(hz, fminf(A[rr].z, A[rr + 2].z));
        e.w = fminf(hw, fminf(A[rr].w, A[rr + 2].w));
        if (ey < 0 || ey >= HH) e = make_float4(-1e10f, -1e10f, -1e10f, -1e10f);
        E[rr] = e;
    }
    __syncthreads();

    #pragma unroll
    for (int d = 0; d < RS; d++) { sx[d * 258 + t + 1] = E[d + 1].x; sw[d * 258 + t + 1] = E[d + 1].w; }
    if (t < RS) { sw[t * 258 + 0] = -1e10f; sx[t * 258 + 257] = -1e10f; }
    __syncthreads();

    float lmin = __uint_as_float(0x7F800000u);
    float lmax = 0.0f;
    #pragma unroll
    for (int d = 0; d < RS; d++) {
        float lw = sw[d * 258 + t], rw = sx[d * 258 + t + 2];
        float4 v = E[d + 1];
        float hx = fmaxf(fmaxf(lw, v.x), v.y);
        float hy = fmaxf(fmaxf(v.x, v.y), v.z);
        float hz = fmaxf(fmaxf(v.y, v.z), v.w);
        float hw = fmaxf(fmaxf(v.z, v.w), rw);
        float4 o;
        o.x = fmaxf(hx, fmaxf(E[d].x, E[d + 2].x));
        o.y = fmaxf(hy, fmaxf(E[d].y, E[d + 2].y));
        o.z = fmaxf(hz, fmaxf(E[d].z, E[d + 2].z));
        o.w = fmaxf(hw, fmaxf(E[d].w, E[d + 2].w));
        outb[(y0 + d) * 256 + t] = o;
        lmin = fminf(lmin, fminf(fminf(o.x, o.y), fminf(o.z, o.w)));
        lmax = fmaxf(lmax, fmaxf(fmaxf(o.x, o.y), fmaxf(o.z, o.w)));
    }
    for (int off = 32; off > 0; off >>= 1) {
        lmin = fminf(lmin, __shfl_down(lmin, off));
        lmax = fmaxf(lmax, __shfl_down(lmax, off));
    }
    if ((t & 63) == 0) { smin[t >> 6] = lmin; smax[t >> 6] = lmax; }
    __syncthreads();
    if (t == 0) {
        float m0 = fminf(fminf(smin[0], smin[1]), fminf(smin[2], smin[3]));
        float m1 = fmaxf(fmaxf(smax[0], smax[1]), fmaxf(smax[2], smax[3]));
        atomicMax(&c[0], ~__float_as_uint(m0));  // complement: min via max, init 0 ok
        atomicMax(&c[1], __float_as_uint(m1));
    }
}

// exact binarize threshold: smallest float B with (B-mn)/denom >= 0.5;
// v >= B is then bitwise identical to the reference predicate for every v.
__device__ __forceinline__ float calc_thr(const uint32_t* c, int bank) {
    float mn = __uint_as_float(~c[bank * 16 + 0]);
    float mx = __uint_as_float(c[bank * 16 + 1]);
    float denom = (mx - mn) + 1e-10f;   // reference association order
    uint32_t lo = 0, hi = 0x7F800000u;
    while (lo < hi) {
        uint32_t mid = (lo + hi) >> 1;
        float q = (__uint_as_float(mid) - mn) / denom;  // IEEE f32 div
        if (q >= 0.5f) hi = mid; else lo = mid + 1;
    }
    return __uint_as_float(lo);
}

// ---------------- LDS union-find (wave-private region) ----------------------
__device__ __forceinline__ uint32_t lload(uint32_t* lp, uint32_t x) {
    return __hip_atomic_load(&lp[x], __ATOMIC_RELAXED, __HIP_MEMORY_SCOPE_WORKGROUP);
}
__device__ __forceinline__ uint32_t lfind(uint32_t* lp, uint32_t x) {
    uint32_t p = lload(lp, x);
    while (p != x) {
        uint32_t gp = lload(lp, p);
        if (gp != p)
            __hip_atomic_store(&lp[x], gp, __ATOMIC_RELAXED, __HIP_MEMORY_SCOPE_WORKGROUP);
        x = p; p = gp;
    }
    return x;
}
__device__ uint32_t lunion(uint32_t* lp, uint32_t a, uint32_t b) {
    uint32_t ra = lfind(lp, a), rb = lfind(lp, b);
    while (ra != rb) {
        uint32_t hi = ra > rb ? ra : rb;
        uint32_t lo = ra ^ rb ^ hi;
        uint32_t old = atomicCAS(&lp[lo], lo, hi);
        if (old == lo) return 1;  // killed exactly one root
        ra = lfind(lp, old);
        rb = lfind(lp, hi);
    }
    return 0;
}
__device__ __forceinline__ int run_len(uint32_t bits) {  // consecutive 1s from bit 0
    return (int)__builtin_ctzll(~(uint64_t)bits);
}

// ---- binarize + tile-local run CCL + compact border-node emit --------------
// UF labels are RUN indices (row*16 + run#, <=16 runs per 32-pixel row), not
// pixel indices: LP/SM shrink 4KB->2KB each => 16.9KB LDS/block => 8 blocks/CU
// (was 4). Same union structure: the verified code only ever unions run reps;
// runIdx = popc(row_starts & mask_up_to(run_end)) - 1 is a bijective rename,
// so runs/links/slot assignment are exactly preserved.
__device__ void do_ccl_tile(const float* __restrict__ opened, uint8_t* __restrict__ desc,
                            uint32_t* __restrict__ parent, uint32_t* cbase, int bank,
                            int tile, int L, uint32_t* M, uint32_t* LP, uint32_t* SM,
                            float thr, uint32_t* pkslot) {
    int b  = tile >> 10;
    int tt = tile & 1023;
    int ty0 = (tt >> 5) << 5;
    int tx0 = (tt & 31) << 5;
    uint32_t base = (uint32_t)b * HW + (uint32_t)ty0 * WW + tx0;

    #pragma unroll
    for (int q = 0; q < 2; q++) {          // 512-entry LP/SM: 128 uint4 each
        uint32_t u = (uint32_t)L + 64u * q;
        ((uint4*)LP)[u] = make_uint4(4*u, 4*u+1, 4*u+2, 4*u+3);
        ((uint4*)SM)[u] = make_uint4(INVALID, INVALID, INVALID, INVALID);
    }

    // dense loads: lane L covers row (L>>3)+8q, cols (L&7)*4..+3
    int r8 = L >> 3, c8 = (L & 7) << 2;
    uint32_t fgcnt = 0;
    #pragma unroll
    for (int q = 0; q < 4; q++) {
        int rr = r8 + 8 * q;
        float4 v = *(const float4*)(opened + base + (uint32_t)rr * WW + c8);
        uint32_t pb = (v.x >= thr ? 1u : 0u) | (v.y >= thr ? 2u : 0u)
                    | (v.z >= thr ? 4u : 0u) | (v.w >= thr ? 8u : 0u);
        fgcnt += __popc(pb);
        uint32_t part = pb << c8;
        part |= __shfl_xor(part, 1, 8);
        part |= __shfl_xor(part, 2, 8);
        part |= __shfl_xor(part, 4, 8);
        if ((L & 7) == 0) M[rr] = part;
    }
    __syncthreads();

    // unions: lane owns half-row (r = L>>1, half h = L&1)
    int r = L >> 1, h = L & 1;
    uint32_t rowm = M[r];
    uint32_t fstarts = rowm & ~(rowm << 1);        // full-row run starts
    uint32_t halfsel = 0xFFFFu << (16 * h);
    uint32_t starts = fstarts & halfsel;
    uint32_t runs = __popc(starts);
    uint32_t links = 0;
    if (r > 0 && starts) {
        uint32_t up = M[r - 1];
        uint32_t upstarts = up & ~(up << 1);
        uint32_t w0 = starts;
        while (w0) {
            int lx = __builtin_ctz(w0); w0 &= w0 - 1;
            int e = lx + run_len(rowm >> lx) - 1;
            int lo = lx ? lx - 1 : 0;
            int hi = (e >= 31) ? 31 : e + 1;
            uint32_t hm = (hi == 31) ? 0xFFFFFFFFu : ((1u << (hi + 1)) - 1u);
            uint32_t w = up & hm & ~((1u << lo) - 1u);
            // (2u<<e)-1 = ones up to bit e inclusive (e=31 -> 0xFFFFFFFF)
            uint32_t repA = ((uint32_t)r << 4) + __popc(fstarts & ((2u << e) - 1u)) - 1u;
            while (w) {
                int xs = __builtin_ctz(w);
                int xe = xs + run_len(up >> xs) - 1;
                uint32_t repB = (((uint32_t)r - 1) << 4)
                              + __popc(upstarts & ((2u << xe) - 1u)) - 1u;
                links += lunion(LP, repA, repB);
                w = (xe >= 31) ? 0u : (w & ~((1u << (xe + 1)) - 1u));
            }
        }
    }
    __syncthreads();

    // pixel-0 / label-0: isolated fg singleton at pixel 0 (all nbrs intra-tile)
    // pixel 0 fg => its run is run 0 of row 0 => label 0; LP[0]==0 <=> still root
    if (tile == 0 && L == 0) {
        if ((rowm & 1u) && !(rowm & 2u) && LP[0] == 0u) atomicOr(&cbase[bank * 16 + 2], 1u);
    }

    // border slot assignment: lane handles positions 2L, 2L+1; lfind from the
    // pixel's RUN label — non-rep runs are never linked in LP.
    uint32_t rk[2]; bool fgk[2];
    #pragma unroll
    for (int j = 0; j < 2; j++) {
        int k = 2 * L + j;
        int li = (k < 32) ? k
               : (k < 64) ? (31 * 32 + (k - 32))
               : (k < 96) ? ((k - 64) << 5)
                          : (((k - 96) << 5) + 31);
        int ly = li >> 5, lx = li & 31;
        uint32_t rm = M[ly];
        bool f = (rm >> lx) & 1u;
        fgk[j] = f;
        if (f) {
            int e = lx + run_len(rm >> lx) - 1;
            uint32_t rst = rm & ~(rm << 1);
            uint32_t lbl = ((uint32_t)ly << 4) + __popc(rst & ((2u << e) - 1u)) - 1u;
            rk[j] = lfind(LP, lbl);
            atomicMin(&SM[rk[j]], (uint32_t)k);
        }
    }
    __syncthreads();

    uint32_t nodebase = (uint32_t)tile << 7;
    uint32_t d2 = 0;
    #pragma unroll
    for (int j = 0; j < 2; j++) {
        int k = 2 * L + j;
        uint32_t sb = 0xFFu;
        if (fgk[j]) {
            uint32_t s = SM[rk[j]];
            sb = s;
            if (s == (uint32_t)k) parent[nodebase + k] = nodebase + k;  // canonical only
        }
        d2 |= sb << (8 * j);
    }
    ((uint16_t*)desc)[((uint32_t)tile << 6) + L] = (uint16_t)d2;

    uint32_t pk = (fgcnt << 20) | (runs << 10) | links;
    for (int off = 32; off > 0; off >>= 1) pk += __shfl_down(pk, off);
    if (L == 0) *pkslot = pk;     // per-wave LDS slot; block combines -> 1 atomic
    __syncthreads();
}

// ---------------- global union-find on compact nodes (device scope) ---------
__device__ __forceinline__ uint32_t pload(uint32_t* P, uint32_t x) {
    return __hip_atomic_load(&P[x], __ATOMIC_RELAXED, __HIP_MEMORY_SCOPE_AGENT);
}
__device__ __forceinline__ uint32_t uf_find(uint32_t* P, uint32_t x) {
    uint32_t p = pload(P, x);
    while (p != x) {
        uint32_t gp = pload(P, p);
        if (gp != p)
            __hip_atomic_store(&P[x], gp, __ATOMIC_RELAXED, __HIP_MEMORY_SCOPE_AGENT);
        x = p; p = gp;
    }
    return x;
}
__device__ uint32_t uf_union(uint32_t* P, uint32_t a, uint32_t b) {
    uint32_t ra = uf_find(P, a);
    uint32_t rb = uf_find(P, b);
    while (ra != rb) {
        uint32_t hi = ra > rb ? ra : rb;
        uint32_t lo = ra ^ rb ^ hi;
        uint32_t old = atomicCAS(&P[lo], lo, hi);
        if (old == lo) return 1;  // killed exactly one root
        ra = uf_find(P, old);
        rb = uf_find(P, hi);
    }
    return 0;
}

// ---------------- kernels: both inputs per dispatch -------------------------
__global__ void k_open2(const float* __restrict__ img, const float* __restrict__ lab,
                        float* __restrict__ op0, float* __restrict__ op1,
                        uint32_t* cbase) {
    __shared__ uint32_t S[5168];
    int bank = blockIdx.x >> 9;
    do_open_strip(bank ? lab : img, bank ? op1 : op0, cbase + bank * 16,
                  blockIdx.x & 511, S);
}

__global__ __launch_bounds__(256, 8) void k_ccl2(const float* __restrict__ op0,
                                                 const float* __restrict__ op1,
                                                 uint8_t* __restrict__ d0,
                                                 uint8_t* __restrict__ d1,
                                                 uint32_t* __restrict__ p0,
                                                 uint32_t* __restrict__ p1,
                                                 uint32_t* cbase) {
    __shared__ uint32_t S[4228];
    int bank = blockIdx.x >> 10;
    int wave = threadIdx.x >> 6, L = threadIdx.x & 63;
    uint32_t* M = S + wave * 1056;       // M[32] | LP[512] | SM[512]
    float thr = calc_thr(cbase, bank);
    int tile = ((blockIdx.x & 1023) << 2) + wave;
    do_ccl_tile(bank ? op1 : op0, bank ? d1 : d0, bank ? p1 : p0, cbase, bank,
                tile, L, M, M + 32, M + 544, thr, &S[4224 + wave]);
    if (threadIdx.x == 0) {
        uint32_t fg = 0, comp = 0;
        #pragma unroll
        for (int w = 0; w < 4; w++) {
            uint32_t pk = S[4224 + w];
            fg   += pk >> 20;
            comp += ((pk >> 10) & 1023u) - (pk & 1023u);   // per-tile runs-links >= 0
        }
        if (fg | comp)
            atomicAdd((unsigned long long*)&cbase[FCW(bank, blockIdx.x & 63)],
                      ((unsigned long long)comp << 32) | fg);
    }
}

// cross-tile edges: candidate (a,b) pairs (r3-verified dedup set) pushed into
// a per-block LDS queue, unioned by all 256 threads round-robin. UF kill count
// is order-invariant, so `links` is exactly preserved.
__global__ __launch_bounds__(256) void k_border(const uint8_t* __restrict__ desc0,
                                                const uint8_t* __restrict__ desc1,
                                                uint32_t* __restrict__ parent0,
                                                uint32_t* __restrict__ parent1,
                                                uint32_t* cbase,
                                                float* __restrict__ out) {
    __shared__ unsigned long long Q[800];   // worst case 4*190+8 = 768 pairs
    __shared__ uint32_t qn;
    __shared__ uint32_t SW[6];
    __shared__ unsigned long long SB[4];
    int inb  = blockIdx.x >> 10;
    int wave = threadIdx.x >> 6, L = threadIdx.x & 63;
    int tile = ((blockIdx.x & 1023) << 2) + wave;
    const uint8_t* desc = inb ? desc1 : desc0;
    uint32_t* parent = inb ? parent1 : parent0;

    if (threadIdx.x == 0) qn = 0;
    __syncthreads();

    // ---- pair generation (per wave, per tile) ----
    {
        int tt = tile & 1023;
        int tyy = tt >> 5, txx = tt & 31;
        const uint8_t* dT = desc + ((uint32_t)tile << 7);
        uint32_t nT = (uint32_t)tile << 7;

        bool east  = (L < 32);
        int  x     = L & 31;
        bool valid = east ? (txx < 31) : (tyy < 31);
        int  tP    = east ? (tile + 1) : (tile + 32);
        uint32_t nP = (uint32_t)tP << 7;
        uint32_t sA = (uint32_t)dT[(east ? 96 : 32) + x];          // own-edge slot
        const uint8_t* dP = desc + (((uint32_t)tP << 7) + (east ? 64u : 0u));
        uint32_t t = valid ? (uint32_t)dP[x] : 0xFFu;              // partner slot

        uint32_t tp1  = __shfl(t,  L + 1);
        uint32_t tm1  = __shfl(t,  L - 1);
        uint32_t sAp1 = __shfl(sA, L + 1);
        uint32_t sAm1 = __shfl(sA, L - 1);

        if (valid && sA != 0xFFu) {
            uint32_t a = nT + sA;
            if (t != 0xFFu && !(x > 0 && sAm1 == sA && tm1 == t)) {
                uint32_t i = atomicAdd(&qn, 1u);
                Q[i] = ((unsigned long long)a << 32) | (nP + t);
            }
            if (x < 31 && tp1 != 0xFFu && tp1 != t && sAp1 != sA) {
                uint32_t i = atomicAdd(&qn, 1u);
                Q[i] = ((unsigned long long)a << 32) | (nP + tp1);
            }
            if (x > 0 && tm1 != 0xFFu && tm1 != t && sAm1 != sA) {
                uint32_t i = atomicAdd(&qn, 1u);
                Q[i] = ((unsigned long long)a << 32) | (nP + tm1);
            }
        }
        if (L == 0 && tyy < 31 && txx < 31) {        // SE corner
            int tSE = tile + 33;
            uint32_t sB = dT[63];
            uint32_t sQ = desc[((uint32_t)tSE << 7)];
            if (sB != 0xFFu && sQ != 0xFFu) {
                uint32_t i = atomicAdd(&qn, 1u);
                Q[i] = ((unsigned long long)(nT + sB) << 32) | (((uint32_t)tSE << 7) + sQ);
            }
        }
        if (L == 1 && tyy < 31 && txx > 0) {         // SW corner
            int tSW = tile + 31;
            uint32_t sB = dT[32];
            uint32_t sQ = desc[((uint32_t)tSW << 7) + 31];
            if (sB != 0xFFu && sQ != 0xFFu) {
                uint32_t i = atomicAdd(&qn, 1u);
                Q[i] = ((unsigned long long)(nT + sB) << 32) | (((uint32_t)tSW << 7) + sQ);
            }
        }
    }
    __syncthreads();

    // ---- rebalanced union phase: all 256 threads share the queue ----
    uint32_t n = qn;
    uint32_t links = 0;
    for (uint32_t i = threadIdx.x; i < n; i += 256) {
        unsigned long long q = Q[i];
        links += uf_union(parent, (uint32_t)(q >> 32), (uint32_t)q);
    }

    for (int off = 32; off > 0; off >>= 1) links += __shfl_down(links, off);
    if (L == 0) SW[wave] = links;
    __syncthreads();
    if (threadIdx.x == 0) {
        uint32_t lk = SW[0] + SW[1] + SW[2] + SW[3];
        if (lk) atomicAdd(&cbase[LKW(inb, blockIdx.x & 63)], lk);
        // order our slot-add before the ticket WITHOUT an agent-release
        // (acq_rel RMW emits L2 cache maintenance per block — the r2
        // regression). All cross-block data moves through device-scope
        // atomics (coherent point), so a plain vmem drain suffices.
        asm volatile("s_waitcnt vmcnt(0)" ::: "memory");
        uint32_t old = __hip_atomic_fetch_add(&cbase[32], 1u,
                                              __ATOMIC_RELAXED, __HIP_MEMORY_SCOPE_AGENT);
        SW[4] = old;
    }
    __syncthreads();
    if (SW[4] == 2047u) {   // last of 2048 blocks: fused final reduce
        unsigned long long acc;
        if (wave == 0)
            acc = __hip_atomic_load((unsigned long long*)&cbase[FCW(0, L)],
                                    __ATOMIC_RELAXED, __HIP_MEMORY_SCOPE_AGENT);
        else if (wave == 1)
            acc = __hip_atomic_load((unsigned long long*)&cbase[FCW(1, L)],
                                    __ATOMIC_RELAXED, __HIP_MEMORY_SCOPE_AGENT);
        else if (wave == 2)
            acc = __hip_atomic_load(&cbase[LKW(0, L)],
                                    __ATOMIC_RELAXED, __HIP_MEMORY_SCOPE_AGENT);
        else
            acc = __hip_atomic_load(&cbase[LKW(1, L)],
                                    __ATOMIC_RELAXED, __HIP_MEMORY_SCOPE_AGENT);
        for (int off = 32; off > 0; off >>= 1) acc += __shfl_down(acc, off);
        if (L == 0) SB[wave] = acc;
        __syncthreads();
        if (threadIdx.x == 0) {
            unsigned long long a0 = SB[0], a1 = SB[1];
            uint32_t gl0 = (uint32_t)SB[2], gl1 = (uint32_t)SB[3];
            uint32_t nf0 = (uint32_t)a0, lc0 = (uint32_t)(a0 >> 32);
            uint32_t nf1 = (uint32_t)a1, lc1 = (uint32_t)(a1 >> 32);
            uint32_t z0 = __hip_atomic_load(&cbase[2],  __ATOMIC_RELAXED, __HIP_MEMORY_SCOPE_AGENT);
            uint32_t z1 = __hip_atomic_load(&cbase[18], __ATOMIC_RELAXED, __HIP_MEMORY_SCOPE_AGENT);
            uint32_t comps0 = lc0 - gl0;   // total fg components (incl. pixel-0 singleton)
            uint32_t comps1 = lc1 - gl1;
            float ccs  = (float)(comps0 - z0 + ((nf0 < (uint32_t)NPIX || z0) ? 1u : 0u));
            float ccsg = (float)(comps1 - z1 + ((nf1 < (uint32_t)NPIX || z1) ? 1u : 0u));
            out[0] = fabsf(ccsg - ccs) / (float)nf1;   // all exact ints < 2^24
        }
    }
}

extern "C" void kernel_launch(void* const* d_in, const int* in_sizes, int n_in,
                              void* d_out, int out_size, void* d_ws, size_t ws_size,
                              hipStream_t stream) {
    const float* img = (const float*)d_in[0];
    const float* lab = (const float*)d_in[1];
    float* out = (float*)d_out;
    char* ws = (char*)d_ws;

    float*    op0 = (float*)ws;                                      // 16 MB
    float*    op1 = (float*)(ws + (size_t)16 * 1024 * 1024);         // 16 MB
    uint8_t*  d0  = (uint8_t*)(ws + (size_t)32 * 1024 * 1024);       // 512 KB
    uint8_t*  d1  = (uint8_t*)(ws + (size_t)32 * 1024 * 1024 + 512 * 1024);
    uint32_t* p0  = (uint32_t*)(ws + (size_t)33 * 1024 * 1024);      // 2 MB
    uint32_t* p1  = (uint32_t*)(ws + (size_t)35 * 1024 * 1024);      // 2 MB
    uint32_t* cnt = (uint32_t*)(ws + (size_t)37 * 1024 * 1024);      // 16640 B

    hipMemsetAsync(cnt, 0, CNT_BYTES, stream);
    k_open2<<<2 * NB * (HH / RS), 256, 0, stream>>>(img, lab, op0, op1, cnt);
    k_ccl2<<<2 * NT / 4, 256, 0, stream>>>(op0, op1, d0, d1, p0, p1, cnt);
    k_border<<<2 * NT / 4, 256, 0, stream>>>(d0, d1, p0, p1, cnt, out);
}

// Round 6
// 130.505 us; speedup vs baseline: 1.1391x; 1.1014x over previous
//
#include <hip/hip_runtime.h>
#include <stdint.h>

#define WW 1024
#define HH 1024
#define NB 4
#define HW (HH * WW)
#define NPIX (NB * HW)        // 4194304
#define NT 4096               // 32x32 tiles per input
#define INVALID 0xFFFFFFFFu
#define RS 8                  // rows per open strip

// aux region (ws+37MB) — NO pre-zeroing, every word is write-before-read and
// fully rewritten each iteration (graph-replay + poison safe):
//   mm  float2[1024] : per-strip (min,max); every open block writes its slot
//   fcs u64[2048]    : per-ccl-block (comp<<32)|fg; every ccl block writes
//   lks u32[2048]    : per-border-block links; every border block writes
//   zt  u32[3]       : [0],[1] root0 flags (ccl, unconditional);
//                      [2] border done-ticket (zeroed by ccl block 0)

// ---- open strip: cross erode+dilate + per-strip min/max (core verified) ----
__device__ __forceinline__ void do_open_strip(const float* __restrict__ in,
                                              float* __restrict__ out,
                                              int strip, uint32_t* S,
                                              float2* __restrict__ mmslot) {
    int b  = strip >> 7;
    int y0 = (strip & 127) * RS;
    int t  = threadIdx.x;
    float* sx = (float*)S;
    float* sw = (float*)S + 2580;
    float* smin = (float*)S + 5160;
    float* smax = (float*)S + 5164;
    const float4* inb = (const float4*)(in + (size_t)b * HW);
    float4* outb      = (float4*)(out + (size_t)b * HW);

    float4 A[RS + 4];
    #pragma unroll
    for (int j = 0; j < RS + 4; j++) {
        int iy = y0 - 2 + j;
        if (iy >= 0 && iy < HH) A[j] = inb[iy * 256 + t];
        else A[j] = make_float4(1e10f, 1e10f, 1e10f, 1e10f);  // erosion pad
    }
    #pragma unroll
    for (int rr = 0; rr < RS + 2; rr++) { sx[rr * 258 + t + 1] = A[rr + 1].x; sw[rr * 258 + t + 1] = A[rr + 1].w; }
    if (t < RS + 2) { sw[t * 258 + 0] = 1e10f; sx[t * 258 + 257] = 1e10f; }
    __syncthreads();

    float4 E[RS + 2];
    #pragma unroll
    for (int rr = 0; rr < RS + 2; rr++) {
        int ey = y0 - 1 + rr;
        float lw = sw[rr * 258 + t], rw = sx[rr * 258 + t + 2];
        float4 v = A[rr + 1];
        float hx = fminf(fminf(lw, v.x), v.y);
        float hy = fminf(fminf(v.x, v.y), v.z);
        float hz = fminf(fminf(v.y, v.z), v.w);
        float hw = fminf(fminf(v.z, v.w), rw);
        float4 e;
        e.x = fminf(hx, fminf(A[rr].x, A[rr + 2].x));
        e.y = fminf(hy, fminf(A[rr].y, A[rr + 2].y));
        e.z = fminf(hz, fminf(A[rr].z, A[rr + 2].z));
        e.w = fminf(hw, fminf(A[rr].w, A[rr + 2].w));
        if (ey < 0 || ey >= HH) e = make_float4(-1e10f, -1e10f, -1e10f, -1e10f);
        E[rr] = e;
    }
    __syncthreads();

    #pragma unroll
    for (int d = 0; d < RS; d++) { sx[d * 258 + t + 1] = E[d + 1].x; sw[d * 258 + t + 1] = E[d + 1].w; }
    if (t < RS) { sw[t * 258 + 0] = -1e10f; sx[t * 258 + 257] = -1e10f; }
    __syncthreads();

    float lmin = __uint_as_float(0x7F800000u);
    float lmax = 0.0f;
    #pragma unroll
    for (int d = 0; d < RS; d++) {
        float lw = sw[d * 258 + t], rw = sx[d * 258 + t + 2];
        float4 v = E[d + 1];
        float hx = fmaxf(fmaxf(lw, v.x), v.y);
        float hy = fmaxf(fmaxf(v.x, v.y), v.z);
        float hz = fmaxf(fmaxf(v.y, v.z), v.w);
        float hw = fmaxf(fmaxf(v.z, v.w), rw);
        float4 o;
        o.x = fmaxf(hx, fmaxf(E[d].x, E[d + 2].x));
        o.y = fmaxf(hy, fmaxf(E[d].y, E[d + 2].y));
        o.z = fmaxf(hz, fmaxf(E[d].z, E[d + 2].z));
        o.w = fmaxf(hw, fmaxf(E[d].w, E[d + 2].w));
        outb[(y0 + d) * 256 + t] = o;
        lmin = fminf(lmin, fminf(fminf(o.x, o.y), fminf(o.z, o.w)));
        lmax = fmaxf(lmax, fmaxf(fmaxf(o.x, o.y), fmaxf(o.z, o.w)));
    }
    for (int off = 32; off > 0; off >>= 1) {
        lmin = fminf(lmin, __shfl_down(lmin, off));
        lmax = fmaxf(lmax, __shfl_down(lmax, off));
    }
    if ((t & 63) == 0) { smin[t >> 6] = lmin; smax[t >> 6] = lmax; }
    __syncthreads();
    if (t == 0) {
        float m0 = fminf(fminf(smin[0], smin[1]), fminf(smin[2], smin[3]));
        float m1 = fmaxf(fmaxf(smax[0], smax[1]), fmaxf(smax[2], smax[3]));
        *mmslot = make_float2(m0, m1);   // plain per-strip slot, no init needed
    }
}

// exact binarize threshold: smallest float B with (B-mn)/denom >= 0.5;
// v >= B is then bitwise identical to the reference predicate for every v.
__device__ __forceinline__ float calc_thr(float mn, float mx) {
    float denom = (mx - mn) + 1e-10f;   // reference association order
    uint32_t lo = 0, hi = 0x7F800000u;
    while (lo < hi) {
        uint32_t mid = (lo + hi) >> 1;
        float q = (__uint_as_float(mid) - mn) / denom;  // IEEE f32 div
        if (q >= 0.5f) hi = mid; else lo = mid + 1;
    }
    return __uint_as_float(lo);
}

// ---------------- LDS union-find (wave-private region) ----------------------
__device__ __forceinline__ uint32_t lload(uint32_t* lp, uint32_t x) {
    return __hip_atomic_load(&lp[x], __ATOMIC_RELAXED, __HIP_MEMORY_SCOPE_WORKGROUP);
}
__device__ __forceinline__ uint32_t lfind(uint32_t* lp, uint32_t x) {
    uint32_t p = lload(lp, x);
    while (p != x) {
        uint32_t gp = lload(lp, p);
        if (gp != p)
            __hip_atomic_store(&lp[x], gp, __ATOMIC_RELAXED, __HIP_MEMORY_SCOPE_WORKGROUP);
        x = p; p = gp;
    }
    return x;
}
__device__ uint32_t lunion(uint32_t* lp, uint32_t a, uint32_t b) {
    uint32_t ra = lfind(lp, a), rb = lfind(lp, b);
    while (ra != rb) {
        uint32_t hi = ra > rb ? ra : rb;
        uint32_t lo = ra ^ rb ^ hi;
        uint32_t old = atomicCAS(&lp[lo], lo, hi);
        if (old == lo) return 1;  // killed exactly one root
        ra = lfind(lp, old);
        rb = lfind(lp, hi);
    }
    return 0;
}
__device__ __forceinline__ int run_len(uint32_t bits) {  // consecutive 1s from bit 0
    return (int)__builtin_ctzll(~(uint64_t)bits);
}

// ---- binarize + tile-local run CCL + compact border-node emit --------------
// UF labels are RUN indices (row*16 + run#): 16.9KB LDS/block => 8 blocks/CU.
__device__ void do_ccl_tile(const float* __restrict__ opened, uint8_t* __restrict__ desc,
                            uint32_t* __restrict__ parent, uint32_t* __restrict__ zt,
                            int bank, int tile, int L,
                            uint32_t* M, uint32_t* LP, uint32_t* SM,
                            float thr, uint32_t* pkslot) {
    int b  = tile >> 10;
    int tt = tile & 1023;
    int ty0 = (tt >> 5) << 5;
    int tx0 = (tt & 31) << 5;
    uint32_t base = (uint32_t)b * HW + (uint32_t)ty0 * WW + tx0;

    #pragma unroll
    for (int q = 0; q < 2; q++) {          // 512-entry LP/SM: 128 uint4 each
        uint32_t u = (uint32_t)L + 64u * q;
        ((uint4*)LP)[u] = make_uint4(4*u, 4*u+1, 4*u+2, 4*u+3);
        ((uint4*)SM)[u] = make_uint4(INVALID, INVALID, INVALID, INVALID);
    }

    // dense loads: lane L covers row (L>>3)+8q, cols (L&7)*4..+3
    int r8 = L >> 3, c8 = (L & 7) << 2;
    uint32_t fgcnt = 0;
    #pragma unroll
    for (int q = 0; q < 4; q++) {
        int rr = r8 + 8 * q;
        float4 v = *(const float4*)(opened + base + (uint32_t)rr * WW + c8);
        uint32_t pb = (v.x >= thr ? 1u : 0u) | (v.y >= thr ? 2u : 0u)
                    | (v.z >= thr ? 4u : 0u) | (v.w >= thr ? 8u : 0u);
        fgcnt += __popc(pb);
        uint32_t part = pb << c8;
        part |= __shfl_xor(part, 1, 8);
        part |= __shfl_xor(part, 2, 8);
        part |= __shfl_xor(part, 4, 8);
        if ((L & 7) == 0) M[rr] = part;
    }
    __syncthreads();

    // unions: lane owns half-row (r = L>>1, half h = L&1)
    int r = L >> 1, h = L & 1;
    uint32_t rowm = M[r];
    uint32_t fstarts = rowm & ~(rowm << 1);        // full-row run starts
    uint32_t halfsel = 0xFFFFu << (16 * h);
    uint32_t starts = fstarts & halfsel;
    uint32_t runs = __popc(starts);
    uint32_t links = 0;
    if (r > 0 && starts) {
        uint32_t up = M[r - 1];
        uint32_t upstarts = up & ~(up << 1);
        uint32_t w0 = starts;
        while (w0) {
            int lx = __builtin_ctz(w0); w0 &= w0 - 1;
            int e = lx + run_len(rowm >> lx) - 1;
            int lo = lx ? lx - 1 : 0;
            int hi = (e >= 31) ? 31 : e + 1;
            uint32_t hm = (hi == 31) ? 0xFFFFFFFFu : ((1u << (hi + 1)) - 1u);
            uint32_t w = up & hm & ~((1u << lo) - 1u);
            // (2u<<e)-1 = ones up to bit e inclusive (e=31 -> 0xFFFFFFFF)
            uint32_t repA = ((uint32_t)r << 4) + __popc(fstarts & ((2u << e) - 1u)) - 1u;
            while (w) {
                int xs = __builtin_ctz(w);
                int xe = xs + run_len(up >> xs) - 1;
                uint32_t repB = (((uint32_t)r - 1) << 4)
                              + __popc(upstarts & ((2u << xe) - 1u)) - 1u;
                links += lunion(LP, repA, repB);
                w = (xe >= 31) ? 0u : (w & ~((1u << (xe + 1)) - 1u));
            }
        }
    }
    __syncthreads();

    // pixel-0 / label-0: isolated fg singleton at pixel 0 (all nbrs intra-tile)
    // pixel 0 fg => its run is run 0 of row 0 => label 0; LP[0]==0 <=> root.
    // Unconditional 0/1 plain store: no zero-init of the flag word needed.
    if (tile == 0 && L == 0)
        zt[bank] = ((rowm & 1u) && !(rowm & 2u) && LP[0] == 0u) ? 1u : 0u;

    // border slot assignment: lane handles positions 2L, 2L+1; lfind from the
    // pixel's RUN label — non-rep runs are never linked in LP.
    uint32_t rk[2]; bool fgk[2];
    #pragma unroll
    for (int j = 0; j < 2; j++) {
        int k = 2 * L + j;
        int li = (k < 32) ? k
               : (k < 64) ? (31 * 32 + (k - 32))
               : (k < 96) ? ((k - 64) << 5)
                          : (((k - 96) << 5) + 31);
        int ly = li >> 5, lx = li & 31;
        uint32_t rm = M[ly];
        bool f = (rm >> lx) & 1u;
        fgk[j] = f;
        if (f) {
            int e = lx + run_len(rm >> lx) - 1;
            uint32_t rst = rm & ~(rm << 1);
            uint32_t lbl = ((uint32_t)ly << 4) + __popc(rst & ((2u << e) - 1u)) - 1u;
            rk[j] = lfind(LP, lbl);
            atomicMin(&SM[rk[j]], (uint32_t)k);
        }
    }
    __syncthreads();

    uint32_t nodebase = (uint32_t)tile << 7;
    uint32_t d2 = 0;
    #pragma unroll
    for (int j = 0; j < 2; j++) {
        int k = 2 * L + j;
        uint32_t sb = 0xFFu;
        if (fgk[j]) {
            uint32_t s = SM[rk[j]];
            sb = s;
            if (s == (uint32_t)k) parent[nodebase + k] = nodebase + k;  // canonical only
        }
        d2 |= sb << (8 * j);
    }
    ((uint16_t*)desc)[((uint32_t)tile << 6) + L] = (uint16_t)d2;

    uint32_t pk = (fgcnt << 20) | (runs << 10) | links;
    for (int off = 32; off > 0; off >>= 1) pk += __shfl_down(pk, off);
    if (L == 0) *pkslot = pk;     // per-wave LDS slot; block combines -> 1 store
    __syncthreads();
}

// ---------------- global union-find on compact nodes (device scope) ---------
__device__ __forceinline__ uint32_t pload(uint32_t* P, uint32_t x) {
    return __hip_atomic_load(&P[x], __ATOMIC_RELAXED, __HIP_MEMORY_SCOPE_AGENT);
}
__device__ __forceinline__ uint32_t uf_find(uint32_t* P, uint32_t x) {
    uint32_t p = pload(P, x);
    while (p != x) {
        uint32_t gp = pload(P, p);
        if (gp != p)
            __hip_atomic_store(&P[x], gp, __ATOMIC_RELAXED, __HIP_MEMORY_SCOPE_AGENT);
        x = p; p = gp;
    }
    return x;
}
__device__ uint32_t uf_union(uint32_t* P, uint32_t a, uint32_t b) {
    uint32_t ra = uf_find(P, a);
    uint32_t rb = uf_find(P, b);
    while (ra != rb) {
        uint32_t hi = ra > rb ? ra : rb;
        uint32_t lo = ra ^ rb ^ hi;
        uint32_t old = atomicCAS(&P[lo], lo, hi);
        if (old == lo) return 1;  // killed exactly one root
        ra = uf_find(P, old);
        rb = uf_find(P, hi);
    }
    return 0;
}

// ---------------- kernels: both inputs per dispatch -------------------------
__global__ void k_open2(const float* __restrict__ img, const float* __restrict__ lab,
                        float* __restrict__ op0, float* __restrict__ op1,
                        float2* __restrict__ mm) {
    __shared__ uint32_t S[5168];
    int bank = blockIdx.x >> 9;
    do_open_strip(bank ? lab : img, bank ? op1 : op0,
                  blockIdx.x & 511, S, &mm[blockIdx.x]);
}

__global__ __launch_bounds__(256, 8) void k_ccl2(const float* __restrict__ op0,
                                                 const float* __restrict__ op1,
                                                 uint8_t* __restrict__ d0,
                                                 uint8_t* __restrict__ d1,
                                                 uint32_t* __restrict__ p0,
                                                 uint32_t* __restrict__ p1,
                                                 const float2* __restrict__ mm,
                                                 unsigned long long* __restrict__ fcs,
                                                 uint32_t* __restrict__ zt) {
    __shared__ uint32_t S[4240];
    int bank = blockIdx.x >> 10;
    int wave = threadIdx.x >> 6, L = threadIdx.x & 63;
    if (blockIdx.x == 0 && threadIdx.x == 0) zt[2] = 0;   // border ticket init
    // per-bank min/max from the 512 strip slots (kernel-boundary visible)
    {
        const float2* mb = mm + (bank << 9);
        float2 u = mb[threadIdx.x];
        float2 v = mb[threadIdx.x + 256];
        float mn = fminf(u.x, v.x), mx = fmaxf(u.y, v.y);
        for (int off = 32; off > 0; off >>= 1) {
            mn = fminf(mn, __shfl_down(mn, off));
            mx = fmaxf(mx, __shfl_down(mx, off));
        }
        float* sf = (float*)(S + 4228);
        if (L == 0) { sf[wave] = mn; sf[4 + wave] = mx; }
    }
    __syncthreads();
    float* sf = (float*)(S + 4228);
    float mnA = fminf(fminf(sf[0], sf[1]), fminf(sf[2], sf[3]));
    float mxA = fmaxf(fmaxf(sf[4], sf[5]), fmaxf(sf[6], sf[7]));
    float thr = calc_thr(mnA, mxA);   // min/max are exact => identical result
    uint32_t* M = S + wave * 1056;    // M[32] | LP[512] | SM[512]
    int tile = ((blockIdx.x & 1023) << 2) + wave;
    do_ccl_tile(bank ? op1 : op0, bank ? d1 : d0, bank ? p1 : p0, zt, bank,
                tile, L, M, M + 32, M + 544, thr, &S[4224 + wave]);
    if (threadIdx.x == 0) {
        uint32_t fg = 0, comp = 0;
        #pragma unroll
        for (int w = 0; w < 4; w++) {
            uint32_t pk = S[4224 + w];
            fg   += pk >> 20;
            comp += ((pk >> 10) & 1023u) - (pk & 1023u);   // per-tile runs-links >= 0
        }
        fcs[blockIdx.x] = ((unsigned long long)comp << 32) | fg;  // unconditional
    }
}

// cross-tile edges: candidate (a,b) pairs (verified dedup set) pushed into a
// per-block LDS queue, unioned by all 256 threads round-robin. UF kill count
// is order-invariant, so `links` is exactly preserved.
__global__ __launch_bounds__(256) void k_border(const uint8_t* __restrict__ desc0,
                                                const uint8_t* __restrict__ desc1,
                                                uint32_t* __restrict__ parent0,
                                                uint32_t* __restrict__ parent1,
                                                unsigned long long* __restrict__ fcs,
                                                uint32_t* __restrict__ lks,
                                                uint32_t* __restrict__ zt,
                                                float* __restrict__ out) {
    __shared__ unsigned long long Q[800];   // worst case 4*190+8 = 768 pairs
    __shared__ uint32_t qn;
    __shared__ uint32_t SW[6];
    __shared__ unsigned long long SB[8];
    __shared__ uint32_t SL[8];
    int inb  = blockIdx.x >> 10;
    int wave = threadIdx.x >> 6, L = threadIdx.x & 63;
    int tile = ((blockIdx.x & 1023) << 2) + wave;
    const uint8_t* desc = inb ? desc1 : desc0;
    uint32_t* parent = inb ? parent1 : parent0;

    if (threadIdx.x == 0) qn = 0;
    __syncthreads();

    // ---- pair generation (per wave, per tile) ----
    {
        int tt = tile & 1023;
        int tyy = tt >> 5, txx = tt & 31;
        const uint8_t* dT = desc + ((uint32_t)tile << 7);
        uint32_t nT = (uint32_t)tile << 7;

        bool east  = (L < 32);
        int  x     = L & 31;
        bool valid = east ? (txx < 31) : (tyy < 31);
        int  tP    = east ? (tile + 1) : (tile + 32);
        uint32_t nP = (uint32_t)tP << 7;
        uint32_t sA = (uint32_t)dT[(east ? 96 : 32) + x];          // own-edge slot
        const uint8_t* dP = desc + (((uint32_t)tP << 7) + (east ? 64u : 0u));
        uint32_t t = valid ? (uint32_t)dP[x] : 0xFFu;              // partner slot

        uint32_t tp1  = __shfl(t,  L + 1);
        uint32_t tm1  = __shfl(t,  L - 1);
        uint32_t sAp1 = __shfl(sA, L + 1);
        uint32_t sAm1 = __shfl(sA, L - 1);

        if (valid && sA != 0xFFu) {
            uint32_t a = nT + sA;
            if (t != 0xFFu && !(x > 0 && sAm1 == sA && tm1 == t)) {
                uint32_t i = atomicAdd(&qn, 1u);
                Q[i] = ((unsigned long long)a << 32) | (nP + t);
            }
            if (x < 31 && tp1 != 0xFFu && tp1 != t && sAp1 != sA) {
                uint32_t i = atomicAdd(&qn, 1u);
                Q[i] = ((unsigned long long)a << 32) | (nP + tp1);
            }
            if (x > 0 && tm1 != 0xFFu && tm1 != t && sAm1 != sA) {
                uint32_t i = atomicAdd(&qn, 1u);
                Q[i] = ((unsigned long long)a << 32) | (nP + tm1);
            }
        }
        if (L == 0 && tyy < 31 && txx < 31) {        // SE corner
            int tSE = tile + 33;
            uint32_t sB = dT[63];
            uint32_t sQ = desc[((uint32_t)tSE << 7)];
            if (sB != 0xFFu && sQ != 0xFFu) {
                uint32_t i = atomicAdd(&qn, 1u);
                Q[i] = ((unsigned long long)(nT + sB) << 32) | (((uint32_t)tSE << 7) + sQ);
            }
        }
        if (L == 1 && tyy < 31 && txx > 0) {         // SW corner
            int tSW = tile + 31;
            uint32_t sB = dT[32];
            uint32_t sQ = desc[((uint32_t)tSW << 7) + 31];
            if (sB != 0xFFu && sQ != 0xFFu) {
                uint32_t i = atomicAdd(&qn, 1u);
                Q[i] = ((unsigned long long)(nT + sB) << 32) | (((uint32_t)tSW << 7) + sQ);
            }
        }
    }
    __syncthreads();

    // ---- rebalanced union phase: all 256 threads share the queue ----
    uint32_t n = qn;
    uint32_t links = 0;
    for (uint32_t i = threadIdx.x; i < n; i += 256) {
        unsigned long long q = Q[i];
        links += uf_union(parent, (uint32_t)(q >> 32), (uint32_t)q);
    }

    for (int off = 32; off > 0; off >>= 1) links += __shfl_down(links, off);
    if (L == 0) SW[wave] = links;
    __syncthreads();
    if (threadIdx.x == 0) {
        uint32_t lk = SW[0] + SW[1] + SW[2] + SW[3];
        // per-block plain slot (agent-scope store hits L2, no init needed);
        // vmcnt(0) orders it before the relaxed ticket (the r3-proven pattern:
        // no acq_rel — that cost 15 µs of per-block cache maintenance in r2).
        __hip_atomic_store(&lks[blockIdx.x], lk, __ATOMIC_RELAXED, __HIP_MEMORY_SCOPE_AGENT);
        asm volatile("s_waitcnt vmcnt(0)" ::: "memory");
        uint32_t old = __hip_atomic_fetch_add(&zt[2], 1u,
                                              __ATOMIC_RELAXED, __HIP_MEMORY_SCOPE_AGENT);
        SW[4] = old;
    }
    __syncthreads();
    if (SW[4] == 2047u) {   // last of 2048 blocks: fused final reduce
        unsigned long long a0 = 0, a1 = 0;
        uint32_t l0 = 0, l1 = 0;
        #pragma unroll
        for (int k = 0; k < 4; k++) {
            int i = (int)threadIdx.x + (k << 8);
            a0 += __hip_atomic_load(&fcs[i],        __ATOMIC_RELAXED, __HIP_MEMORY_SCOPE_AGENT);
            a1 += __hip_atomic_load(&fcs[1024 + i], __ATOMIC_RELAXED, __HIP_MEMORY_SCOPE_AGENT);
            l0 += __hip_atomic_load(&lks[i],        __ATOMIC_RELAXED, __HIP_MEMORY_SCOPE_AGENT);
            l1 += __hip_atomic_load(&lks[1024 + i], __ATOMIC_RELAXED, __HIP_MEMORY_SCOPE_AGENT);
        }
        for (int off = 32; off > 0; off >>= 1) {
            a0 += __shfl_down(a0, off);
            a1 += __shfl_down(a1, off);
            l0 += __shfl_down(l0, off);
            l1 += __shfl_down(l1, off);
        }
        if (L == 0) { SB[wave] = a0; SB[4 + wave] = a1; SL[wave] = l0; SL[4 + wave] = l1; }
        __syncthreads();
        if (threadIdx.x == 0) {
            unsigned long long A0 = SB[0] + SB[1] + SB[2] + SB[3];
            unsigned long long A1 = SB[4] + SB[5] + SB[6] + SB[7];
            uint32_t gl0 = SL[0] + SL[1] + SL[2] + SL[3];
            uint32_t gl1 = SL[4] + SL[5] + SL[6] + SL[7];
            uint32_t nf0 = (uint32_t)A0, lc0 = (uint32_t)(A0 >> 32);
            uint32_t nf1 = (uint32_t)A1, lc1 = (uint32_t)(A1 >> 32);
            uint32_t z0 = __hip_atomic_load(&zt[0], __ATOMIC_RELAXED, __HIP_MEMORY_SCOPE_AGENT);
            uint32_t z1 = __hip_atomic_load(&zt[1], __ATOMIC_RELAXED, __HIP_MEMORY_SCOPE_AGENT);
            uint32_t comps0 = lc0 - gl0;   // total fg components (incl. pixel-0 singleton)
            uint32_t comps1 = lc1 - gl1;
            float ccs  = (float)(comps0 - z0 + ((nf0 < (uint32_t)NPIX || z0) ? 1u : 0u));
            float ccsg = (float)(comps1 - z1 + ((nf1 < (uint32_t)NPIX || z1) ? 1u : 0u));
            out[0] = fabsf(ccsg - ccs) / (float)nf1;   // all exact ints < 2^24
        }
    }
}

extern "C" void kernel_launch(void* const* d_in, const int* in_sizes, int n_in,
                              void* d_out, int out_size, void* d_ws, size_t ws_size,
                              hipStream_t stream) {
    const float* img = (const float*)d_in[0];
    const float* lab = (const float*)d_in[1];
    float* out = (float*)d_out;
    char* ws = (char*)d_ws;

    float*    op0 = (float*)ws;                                      // 16 MB
    float*    op1 = (float*)(ws + (size_t)16 * 1024 * 1024);         // 16 MB
    uint8_t*  d0  = (uint8_t*)(ws + (size_t)32 * 1024 * 1024);       // 512 KB
    uint8_t*  d1  = (uint8_t*)(ws + (size_t)32 * 1024 * 1024 + 512 * 1024);
    uint32_t* p0  = (uint32_t*)(ws + (size_t)33 * 1024 * 1024);      // 2 MB
    uint32_t* p1  = (uint32_t*)(ws + (size_t)35 * 1024 * 1024);      // 2 MB
    char*     aux = ws + (size_t)37 * 1024 * 1024;
    float2*   mm  = (float2*)aux;                                    // 8 KB
    unsigned long long* fcs = (unsigned long long*)(aux + 8192);     // 16 KB
    uint32_t* lks = (uint32_t*)(aux + 24576);                        // 8 KB
    uint32_t* zt  = (uint32_t*)(aux + 32768);                        // 12 B

    k_open2<<<2 * NB * (HH / RS), 256, 0, stream>>>(img, lab, op0, op1, mm);
    k_ccl2<<<2 * NT / 4, 256, 0, stream>>>(op0, op1, d0, d1, p0, p1, mm, fcs, zt);
    k_border<<<2 * NT / 4, 256, 0, stream>>>(d0, d1, p0, p1, fcs, lks, zt, out);
}